// Round 2
// baseline (315.737 us; speedup 1.0000x reference)
//
#include <hip/hip_runtime.h>
#include <hip/hip_bf16.h>

// 3-layer GCN, fixed 24-node DAG, batch 65536.
// Transposed-MFMA: each layer computes D^T = W^T * H^T with mfma_f32_16x16x32_bf16.
// Graph agg (fixed coeffs) + bias + relu fused into B-fragment build.
// One wave = 2 samples/iter (48 rows = 3 M-tiles). All LDS is WAVE-PRIVATE:
// no __syncthreads anywhere (same-wave DS ops are in-order; compiler preserves
// may-alias program order). o3 (f32 staging) overlays hbuf (dead by then).

typedef __attribute__((ext_vector_type(8))) short bf16x8;
typedef __attribute__((ext_vector_type(4))) float f32x4;
typedef __attribute__((ext_vector_type(2))) float f32x2;

#define NBLK  1024
#define ITERS 8          // samples/wave = 2*ITERS ; 1024 blk * 4 waves * 16 = 65536

__device__ __forceinline__ unsigned short f2bf(float f) {
  __hip_bfloat16 h = __float2bfloat16(f);
  return __builtin_bit_cast(unsigned short, h);
}
__device__ __forceinline__ f32x2 unpk(unsigned d) {
  f32x2 r;
  r.x = __builtin_bit_cast(float, d << 16);
  r.y = __builtin_bit_cast(float, d & 0xffff0000u);
  return r;
}
__device__ __forceinline__ unsigned pack2(f32x2 v) {
  return (unsigned)f2bf(v.x) | ((unsigned)f2bf(v.y) << 16);
}

union U16 { uint4 u; bf16x8 b; };

__device__ __forceinline__ bf16x8 pack8(const float v[8]) {
  U16 un;
  un.u.x = (unsigned)f2bf(v[0]) | ((unsigned)f2bf(v[1]) << 16);
  un.u.y = (unsigned)f2bf(v[2]) | ((unsigned)f2bf(v[3]) << 16);
  un.u.z = (unsigned)f2bf(v[4]) | ((unsigned)f2bf(v[5]) << 16);
  un.u.w = (unsigned)f2bf(v[6]) | ((unsigned)f2bf(v[7]) << 16);
  return un.b;
}

__global__ __launch_bounds__(256, 4)
void gnn_kernel(const float* __restrict__ xg,  const float* __restrict__ w1g,
                const float* __restrict__ b1g, const float* __restrict__ w3g,
                const float* __restrict__ b3g, const float* __restrict__ w2g,
                const float* __restrict__ b2g, float* __restrict__ outg) {
  // per-wave private LDS: H (pre-agg) bf16 pitch 72; o3 (f32, pitch 20) overlays it
  __shared__ __align__(16) unsigned short hbuf_s[4][48 * 72];  // 6912 B per wave

  const int tid  = threadIdx.x;
  const int w    = tid >> 6;
  const int lane = tid & 63;
  const int l15  = lane & 15;
  const int g    = lane >> 4;
  unsigned short* hb = hbuf_s[w];
  float*          o3 = (float*)hbuf_s[w];   // overlay: 48*20*4 = 3840 B <= 6912 B
  const int wgid = blockIdx.x * 4 + w;

  // ---- static A-operand fragments (transposed weights), built once ----
  bf16x8 w1f[4], w3f[4][2], w2f[2];
  {
    float v[8];
    #pragma unroll
    for (int mi = 0; mi < 4; ++mi) {
      const int c = 16 * mi + l15;
      #pragma unroll
      for (int j = 0; j < 8; ++j) { int k = 8 * g + j; v[j] = (k < 10) ? w1g[k * 64 + c] : 0.f; }
      w1f[mi] = pack8(v);
      #pragma unroll
      for (int ki = 0; ki < 2; ++ki) {
        #pragma unroll
        for (int j = 0; j < 8; ++j) { int k = 32 * ki + 8 * g + j; v[j] = w3g[k * 64 + c]; }
        w3f[mi][ki] = pack8(v);
      }
    }
    #pragma unroll
    for (int ki = 0; ki < 2; ++ki) {
      #pragma unroll
      for (int j = 0; j < 8; ++j) {
        int k = 32 * ki + 8 * g + j;
        v[j] = (l15 < 10) ? w2g[k * 10 + l15] : 0.f;
      }
      w2f[ki] = pack8(v);
    }
  }

  // ---- per-lane bias registers as f32x2 pairs: bias[k], k = 32*ki + 8*g + 2*p+{0,1} ----
  f32x2 b1r[2][4], b3r[2][4];
  #pragma unroll
  for (int ki = 0; ki < 2; ++ki) {
    #pragma unroll
    for (int p = 0; p < 4; ++p) {
      const int k = 32 * ki + 8 * g + 2 * p;
      b1r[ki][p].x = b1g[k]; b1r[ki][p].y = b1g[k + 1];
      b3r[ki][p].x = b3g[k]; b3r[ki][p].y = b3g[k + 1];
    }
  }
  const float b2p = b2g[lane % 10];

  // ---- per-lane graph-agg coefficients for rows r = 16*ni + l15 ----
  int rowA[3], rowB[3], xoff[3];
  float csv[3], cabv[3];
  #pragma unroll
  for (int ni = 0; ni < 3; ++ni) {
    const int r   = 16 * ni + l15;
    const int sub = r / 24;
    const int n   = r - 24 * sub;
    csv[ni]  = (n < 2) ? 1.f : (1.f / 3.f);
    cabv[ni] = (n < 2) ? 0.f : ((n < 4) ? 0.57735026918962576f : (1.f / 3.f));
    const int sA = (n < 4) ? 0 : ((n & ~1) - 2);
    const int sB = (n < 4) ? 1 : ((n & ~1) - 1);
    rowA[ni] = 24 * sub + sA;
    rowB[ni] = 24 * sub + sB;
    xoff[ni] = sub * 240 + n * 10;
  }

  const f32x2 zero2 = {0.f, 0.f};

  // B-frag builder: 3 source rows of pre-agg H -> packed-f32 combine -> bf16
  auto build = [&](int ni, int ki, const f32x2(&bias)[4]) -> bf16x8 {
    const int kbase = 32 * ki + 8 * g;
    const uint4 vS = *(const uint4*)(hb + (16 * ni + l15) * 72 + kbase);
    const uint4 vA = *(const uint4*)(hb + rowA[ni] * 72 + kbase);
    const uint4 vB = *(const uint4*)(hb + rowB[ni] * 72 + kbase);
    const f32x2 cs2  = {csv[ni], csv[ni]};
    const f32x2 cab2 = {cabv[ni], cabv[ni]};
    const unsigned aS[4] = {vS.x, vS.y, vS.z, vS.w};
    const unsigned aA[4] = {vA.x, vA.y, vA.z, vA.w};
    const unsigned aB[4] = {vB.x, vB.y, vB.z, vB.w};
    unsigned d[4];
    #pragma unroll
    for (int p = 0; p < 4; ++p) {
      f32x2 S = unpk(aS[p]);
      f32x2 t = unpk(aA[p]) + unpk(aB[p]);
      f32x2 v = __builtin_elementwise_fma(S, cs2, bias[p]);
      v = __builtin_elementwise_fma(t, cab2, v);
      v = __builtin_elementwise_max(v, zero2);
      d[p] = pack2(v);
    }
    U16 un; un.u.x = d[0]; un.u.y = d[1]; un.u.z = d[2]; un.u.w = d[3];
    return un.b;
  };

  const f32x4 zf = {0.f, 0.f, 0.f, 0.f};

  for (int it = 0; it < ITERS; ++it) {
    const int s0 = wgid * (2 * ITERS) + it * 2;
    const float* xb = xg + (long)s0 * 240;

    // ---------- Layer 1: D1^T = W1^T * X^T (K=10 zero-padded to 32) ----------
    f32x4 acc[4][3];
    #pragma unroll
    for (int ni = 0; ni < 3; ++ni) {
      float v[8] = {0.f, 0.f, 0.f, 0.f, 0.f, 0.f, 0.f, 0.f};
      const float* xr = xb + xoff[ni];
      if (g == 0) {
        float2 p0 = *(const float2*)(xr + 0);
        float2 p1 = *(const float2*)(xr + 2);
        float2 p2 = *(const float2*)(xr + 4);
        float2 p3 = *(const float2*)(xr + 6);
        v[0] = p0.x; v[1] = p0.y; v[2] = p1.x; v[3] = p1.y;
        v[4] = p2.x; v[5] = p2.y; v[6] = p3.x; v[7] = p3.y;
      } else if (g == 1) {
        float2 p4 = *(const float2*)(xr + 8);
        v[0] = p4.x; v[1] = p4.y;
      }
      bf16x8 bx = pack8(v);
      #pragma unroll
      for (int mi = 0; mi < 4; ++mi)
        acc[mi][ni] = __builtin_amdgcn_mfma_f32_16x16x32_bf16(w1f[mi], bx, zf, 0, 0, 0);
    }
    // write pre-agg H1 (bf16): lane holds c = 16*mi+4*g+rr at row r = 16*ni+l15
    #pragma unroll
    for (int mi = 0; mi < 4; ++mi) {
      #pragma unroll
      for (int ni = 0; ni < 3; ++ni) {
        const int r = 16 * ni + l15, cb = 16 * mi + 4 * g;
        uint2 pk;
        pk.x = (unsigned)f2bf(acc[mi][ni][0]) | ((unsigned)f2bf(acc[mi][ni][1]) << 16);
        pk.y = (unsigned)f2bf(acc[mi][ni][2]) | ((unsigned)f2bf(acc[mi][ni][3]) << 16);
        *(uint2*)(hb + r * 72 + cb) = pk;
      }
    }

    // ---------- Layer 2: D2^T = W3^T * relu(agg(H1)+b1)^T ----------
    #pragma unroll
    for (int ni = 0; ni < 3; ++ni) {
      bf16x8 bb0 = build(ni, 0, b1r[0]);
      bf16x8 bb1 = build(ni, 1, b1r[1]);
      #pragma unroll
      for (int mi = 0; mi < 4; ++mi) {
        f32x4 t = __builtin_amdgcn_mfma_f32_16x16x32_bf16(w3f[mi][0], bb0, zf, 0, 0, 0);
        acc[mi][ni] = __builtin_amdgcn_mfma_f32_16x16x32_bf16(w3f[mi][1], bb1, t, 0, 0, 0);
      }
    }
    // write pre-agg H2 (same-wave program order keeps read->write safe)
    #pragma unroll
    for (int mi = 0; mi < 4; ++mi) {
      #pragma unroll
      for (int ni = 0; ni < 3; ++ni) {
        const int r = 16 * ni + l15, cb = 16 * mi + 4 * g;
        uint2 pk;
        pk.x = (unsigned)f2bf(acc[mi][ni][0]) | ((unsigned)f2bf(acc[mi][ni][1]) << 16);
        pk.y = (unsigned)f2bf(acc[mi][ni][2]) | ((unsigned)f2bf(acc[mi][ni][3]) << 16);
        *(uint2*)(hb + r * 72 + cb) = pk;
      }
    }

    // ---------- Layer 3: D3^T = W2^T * relu(agg(H2)+b3)^T ----------
    f32x4 acc3[3];
    #pragma unroll
    for (int ni = 0; ni < 3; ++ni) {
      bf16x8 bb0 = build(ni, 0, b3r[0]);
      bf16x8 bb1 = build(ni, 1, b3r[1]);
      f32x4 t  = __builtin_amdgcn_mfma_f32_16x16x32_bf16(w2f[0], bb0, zf, 0, 0, 0);
      acc3[ni] = __builtin_amdgcn_mfma_f32_16x16x32_bf16(w2f[1], bb1, t, 0, 0, 0);
    }
    // stage pre-agg layer-3 output (f32) over the hbuf space (hb is dead now)
    #pragma unroll
    for (int ni = 0; ni < 3; ++ni) {
      const int r = 16 * ni + l15;
      *(f32x4*)(o3 + r * 20 + 4 * g) = acc3[ni];
    }

    // ---------- epilogue: agg3 + b2 + relu, mean over 24 nodes ----------
    {
      const int part = lane / 10;          // 0..5 valid (lane<60)
      const int pc   = lane - 10 * part;   // output channel 0..9
      #pragma unroll
      for (int sub = 0; sub < 2; ++sub) {
        float sum = 0.f;
        if (lane < 60) {
          const int rb = 24 * sub;
          #pragma unroll
          for (int dn = 0; dn < 4; ++dn) {
            const int n = 4 * part + dn;
            const float cs  = (n < 2) ? 1.f : (1.f / 3.f);
            const float cab = (n < 2) ? 0.f : ((n < 4) ? 0.57735026918962576f : (1.f / 3.f));
            const int sA = (n < 4) ? 0 : ((n & ~1) - 2);
            const int sB = (n < 4) ? 1 : ((n & ~1) - 1);
            const float vv = cs * o3[(rb + n) * 20 + pc]
                           + cab * (o3[(rb + sA) * 20 + pc] + o3[(rb + sB) * 20 + pc]);
            sum += fmaxf(vv + b2p, 0.f);
          }
        }
        float s1 = sum + __shfl_down(sum, 30);
        float t1 = __shfl_down(s1, 10);
        float t2 = __shfl_down(s1, 20);
        float tot = s1 + t1 + t2;
        if (lane < 10) outg[(long)(s0 + sub) * 10 + lane] = tot * (1.f / 24.f);
      }
    }
  }
}

extern "C" void kernel_launch(void* const* d_in, const int* in_sizes, int n_in,
                              void* d_out, int out_size, void* d_ws, size_t ws_size,
                              hipStream_t stream) {
  (void)in_sizes; (void)n_in; (void)d_ws; (void)ws_size; (void)out_size;
  const float* x  = (const float*)d_in[0];
  const float* W1 = (const float*)d_in[1];
  const float* b1 = (const float*)d_in[2];
  const float* W3 = (const float*)d_in[3];
  const float* b3 = (const float*)d_in[4];
  const float* W2 = (const float*)d_in[5];
  const float* b2 = (const float*)d_in[6];
  // d_in[7] = edge_index: fixed compile-time DAG; coefficients hard-coded.
  float* out = (float*)d_out;
  hipLaunchKernelGGL(gnn_kernel, dim3(NBLK), dim3(256), 0, stream,
                     x, W1, b1, W3, b3, W2, b2, out);
}

// Round 3
// 188.679 us; speedup vs baseline: 1.6734x; 1.6734x over previous
//
#include <hip/hip_runtime.h>
#include <hip/hip_bf16.h>

// 3-layer GCN, fixed 24-node DAG, batch 65536.
// Transposed-MFMA: each layer computes D^T = W^T * H^T with mfma_f32_16x16x32_bf16.
// Graph agg (fixed coeffs) + bias + relu fused into B-fragment build.
// One wave = 2 samples/iter (48 rows = 3 M-tiles). All LDS is WAVE-PRIVATE:
// no __syncthreads (same-wave DS ops are in-order). o3 overlays hbuf.
// launch_bounds(256,2): do NOT cap registers harder — weight fragments +
// biases + accumulators are ~136 persistent regs; round-2's (256,4) cap
// caused 650 MB of scratch spill traffic and a 2.3x regression.

typedef __attribute__((ext_vector_type(8))) short bf16x8;
typedef __attribute__((ext_vector_type(4))) float f32x4;
typedef __attribute__((ext_vector_type(2))) float f32x2;

#define NBLK  1024
#define ITERS 8          // samples/wave = 2*ITERS ; 1024 blk * 4 waves * 16 = 65536

__device__ __forceinline__ unsigned short f2bf(float f) {
  __hip_bfloat16 h = __float2bfloat16(f);
  return __builtin_bit_cast(unsigned short, h);
}
__device__ __forceinline__ f32x2 unpk(unsigned d) {
  f32x2 r;
  r.x = __builtin_bit_cast(float, d << 16);
  r.y = __builtin_bit_cast(float, d & 0xffff0000u);
  return r;
}
__device__ __forceinline__ unsigned pack2(f32x2 v) {
  return (unsigned)f2bf(v.x) | ((unsigned)f2bf(v.y) << 16);
}

union U16 { uint4 u; bf16x8 b; };

__device__ __forceinline__ bf16x8 pack8(const float v[8]) {
  U16 un;
  un.u.x = (unsigned)f2bf(v[0]) | ((unsigned)f2bf(v[1]) << 16);
  un.u.y = (unsigned)f2bf(v[2]) | ((unsigned)f2bf(v[3]) << 16);
  un.u.z = (unsigned)f2bf(v[4]) | ((unsigned)f2bf(v[5]) << 16);
  un.u.w = (unsigned)f2bf(v[6]) | ((unsigned)f2bf(v[7]) << 16);
  return un.b;
}

__global__ __launch_bounds__(256, 2)
void gnn_kernel(const float* __restrict__ xg,  const float* __restrict__ w1g,
                const float* __restrict__ b1g, const float* __restrict__ w3g,
                const float* __restrict__ b3g, const float* __restrict__ w2g,
                const float* __restrict__ b2g, float* __restrict__ outg) {
  // per-wave private LDS: H (pre-agg) bf16 pitch 72; o3 (f32, pitch 20) overlays it
  __shared__ __align__(16) unsigned short hbuf_s[4][48 * 72];  // 6912 B per wave

  const int tid  = threadIdx.x;
  const int w    = tid >> 6;
  const int lane = tid & 63;
  const int l15  = lane & 15;
  const int g    = lane >> 4;
  unsigned short* hb = hbuf_s[w];
  float*          o3 = (float*)hbuf_s[w];   // overlay: 48*20*4 = 3840 B <= 6912 B
  const int wgid = blockIdx.x * 4 + w;

  // ---- static A-operand fragments (transposed weights), built once ----
  bf16x8 w1f[4], w3f[4][2], w2f[2];
  {
    float v[8];
    #pragma unroll
    for (int mi = 0; mi < 4; ++mi) {
      const int c = 16 * mi + l15;
      #pragma unroll
      for (int j = 0; j < 8; ++j) { int k = 8 * g + j; v[j] = (k < 10) ? w1g[k * 64 + c] : 0.f; }
      w1f[mi] = pack8(v);
      #pragma unroll
      for (int ki = 0; ki < 2; ++ki) {
        #pragma unroll
        for (int j = 0; j < 8; ++j) { int k = 32 * ki + 8 * g + j; v[j] = w3g[k * 64 + c]; }
        w3f[mi][ki] = pack8(v);
      }
    }
    #pragma unroll
    for (int ki = 0; ki < 2; ++ki) {
      #pragma unroll
      for (int j = 0; j < 8; ++j) {
        int k = 32 * ki + 8 * g + j;
        v[j] = (l15 < 10) ? w2g[k * 10 + l15] : 0.f;
      }
      w2f[ki] = pack8(v);
    }
  }

  // ---- per-lane bias registers as f32x2 pairs: bias[k], k = 32*ki + 8*g + 2*p+{0,1} ----
  f32x2 b1r[2][4], b3r[2][4];
  #pragma unroll
  for (int ki = 0; ki < 2; ++ki) {
    #pragma unroll
    for (int p = 0; p < 4; ++p) {
      const int k = 32 * ki + 8 * g + 2 * p;
      b1r[ki][p].x = b1g[k]; b1r[ki][p].y = b1g[k + 1];
      b3r[ki][p].x = b3g[k]; b3r[ki][p].y = b3g[k + 1];
    }
  }
  const float b2p = b2g[lane % 10];

  // ---- per-lane graph-agg coefficients for rows r = 16*ni + l15 ----
  int rowA[3], rowB[3], xoff[3];
  float csv[3], cabv[3];
  #pragma unroll
  for (int ni = 0; ni < 3; ++ni) {
    const int r   = 16 * ni + l15;
    const int sub = r / 24;
    const int n   = r - 24 * sub;
    csv[ni]  = (n < 2) ? 1.f : (1.f / 3.f);
    cabv[ni] = (n < 2) ? 0.f : ((n < 4) ? 0.57735026918962576f : (1.f / 3.f));
    const int sA = (n < 4) ? 0 : ((n & ~1) - 2);
    const int sB = (n < 4) ? 1 : ((n & ~1) - 1);
    rowA[ni] = 24 * sub + sA;
    rowB[ni] = 24 * sub + sB;
    xoff[ni] = sub * 240 + n * 10;
  }

  const f32x2 zero2 = {0.f, 0.f};

  // B-frag builder: 3 source rows of pre-agg H -> packed-f32 combine -> bf16
  auto build = [&](int ni, int ki, const f32x2(&bias)[4]) -> bf16x8 {
    const int kbase = 32 * ki + 8 * g;
    const uint4 vS = *(const uint4*)(hb + (16 * ni + l15) * 72 + kbase);
    const uint4 vA = *(const uint4*)(hb + rowA[ni] * 72 + kbase);
    const uint4 vB = *(const uint4*)(hb + rowB[ni] * 72 + kbase);
    const f32x2 cs2  = {csv[ni], csv[ni]};
    const f32x2 cab2 = {cabv[ni], cabv[ni]};
    const unsigned aS[4] = {vS.x, vS.y, vS.z, vS.w};
    const unsigned aA[4] = {vA.x, vA.y, vA.z, vA.w};
    const unsigned aB[4] = {vB.x, vB.y, vB.z, vB.w};
    unsigned d[4];
    #pragma unroll
    for (int p = 0; p < 4; ++p) {
      f32x2 S = unpk(aS[p]);
      f32x2 t = unpk(aA[p]) + unpk(aB[p]);
      f32x2 v = __builtin_elementwise_fma(S, cs2, bias[p]);
      v = __builtin_elementwise_fma(t, cab2, v);
      v = __builtin_elementwise_max(v, zero2);
      d[p] = pack2(v);
    }
    U16 un; un.u.x = d[0]; un.u.y = d[1]; un.u.z = d[2]; un.u.w = d[3];
    return un.b;
  };

  const f32x4 zf = {0.f, 0.f, 0.f, 0.f};

  for (int it = 0; it < ITERS; ++it) {
    const int s0 = wgid * (2 * ITERS) + it * 2;
    const float* xb = xg + (long)s0 * 240;

    // ---------- Layer 1: D1^T = W1^T * X^T (K=10 zero-padded to 32) ----------
    f32x4 acc[4][3];
    #pragma unroll
    for (int ni = 0; ni < 3; ++ni) {
      float v[8] = {0.f, 0.f, 0.f, 0.f, 0.f, 0.f, 0.f, 0.f};
      const float* xr = xb + xoff[ni];
      if (g == 0) {
        float2 p0 = *(const float2*)(xr + 0);
        float2 p1 = *(const float2*)(xr + 2);
        float2 p2 = *(const float2*)(xr + 4);
        float2 p3 = *(const float2*)(xr + 6);
        v[0] = p0.x; v[1] = p0.y; v[2] = p1.x; v[3] = p1.y;
        v[4] = p2.x; v[5] = p2.y; v[6] = p3.x; v[7] = p3.y;
      } else if (g == 1) {
        float2 p4 = *(const float2*)(xr + 8);
        v[0] = p4.x; v[1] = p4.y;
      }
      bf16x8 bx = pack8(v);
      #pragma unroll
      for (int mi = 0; mi < 4; ++mi)
        acc[mi][ni] = __builtin_amdgcn_mfma_f32_16x16x32_bf16(w1f[mi], bx, zf, 0, 0, 0);
    }
    // write pre-agg H1 (bf16): lane holds c = 16*mi+4*g+rr at row r = 16*ni+l15
    #pragma unroll
    for (int mi = 0; mi < 4; ++mi) {
      #pragma unroll
      for (int ni = 0; ni < 3; ++ni) {
        const int r = 16 * ni + l15, cb = 16 * mi + 4 * g;
        uint2 pk;
        pk.x = (unsigned)f2bf(acc[mi][ni][0]) | ((unsigned)f2bf(acc[mi][ni][1]) << 16);
        pk.y = (unsigned)f2bf(acc[mi][ni][2]) | ((unsigned)f2bf(acc[mi][ni][3]) << 16);
        *(uint2*)(hb + r * 72 + cb) = pk;
      }
    }

    // ---------- Layer 2: D2^T = W3^T * relu(agg(H1)+b1)^T ----------
    #pragma unroll
    for (int ni = 0; ni < 3; ++ni) {
      bf16x8 bb0 = build(ni, 0, b1r[0]);
      bf16x8 bb1 = build(ni, 1, b1r[1]);
      #pragma unroll
      for (int mi = 0; mi < 4; ++mi) {
        f32x4 t = __builtin_amdgcn_mfma_f32_16x16x32_bf16(w3f[mi][0], bb0, zf, 0, 0, 0);
        acc[mi][ni] = __builtin_amdgcn_mfma_f32_16x16x32_bf16(w3f[mi][1], bb1, t, 0, 0, 0);
      }
    }
    // write pre-agg H2 (same-wave program order keeps read->write safe)
    #pragma unroll
    for (int mi = 0; mi < 4; ++mi) {
      #pragma unroll
      for (int ni = 0; ni < 3; ++ni) {
        const int r = 16 * ni + l15, cb = 16 * mi + 4 * g;
        uint2 pk;
        pk.x = (unsigned)f2bf(acc[mi][ni][0]) | ((unsigned)f2bf(acc[mi][ni][1]) << 16);
        pk.y = (unsigned)f2bf(acc[mi][ni][2]) | ((unsigned)f2bf(acc[mi][ni][3]) << 16);
        *(uint2*)(hb + r * 72 + cb) = pk;
      }
    }

    // ---------- Layer 3: D3^T = W2^T * relu(agg(H2)+b3)^T ----------
    f32x4 acc3[3];
    #pragma unroll
    for (int ni = 0; ni < 3; ++ni) {
      bf16x8 bb0 = build(ni, 0, b3r[0]);
      bf16x8 bb1 = build(ni, 1, b3r[1]);
      f32x4 t  = __builtin_amdgcn_mfma_f32_16x16x32_bf16(w2f[0], bb0, zf, 0, 0, 0);
      acc3[ni] = __builtin_amdgcn_mfma_f32_16x16x32_bf16(w2f[1], bb1, t, 0, 0, 0);
    }
    // stage pre-agg layer-3 output (f32) over the hbuf space (hb is dead now)
    #pragma unroll
    for (int ni = 0; ni < 3; ++ni) {
      const int r = 16 * ni + l15;
      *(f32x4*)(o3 + r * 20 + 4 * g) = acc3[ni];
    }

    // ---------- epilogue: agg3 + b2 + relu, mean over 24 nodes ----------
    {
      const int part = lane / 10;          // 0..5 valid (lane<60)
      const int pc   = lane - 10 * part;   // output channel 0..9
      #pragma unroll
      for (int sub = 0; sub < 2; ++sub) {
        float sum = 0.f;
        if (lane < 60) {
          const int rb = 24 * sub;
          #pragma unroll
          for (int dn = 0; dn < 4; ++dn) {
            const int n = 4 * part + dn;
            const float cs  = (n < 2) ? 1.f : (1.f / 3.f);
            const float cab = (n < 2) ? 0.f : ((n < 4) ? 0.57735026918962576f : (1.f / 3.f));
            const int sA = (n < 4) ? 0 : ((n & ~1) - 2);
            const int sB = (n < 4) ? 1 : ((n & ~1) - 1);
            const float vv = cs * o3[(rb + n) * 20 + pc]
                           + cab * (o3[(rb + sA) * 20 + pc] + o3[(rb + sB) * 20 + pc]);
            sum += fmaxf(vv + b2p, 0.f);
          }
        }
        float s1 = sum + __shfl_down(sum, 30);
        float t1 = __shfl_down(s1, 10);
        float t2 = __shfl_down(s1, 20);
        float tot = s1 + t1 + t2;
        if (lane < 10) outg[(long)(s0 + sub) * 10 + lane] = tot * (1.f / 24.f);
      }
    }
  }
}

extern "C" void kernel_launch(void* const* d_in, const int* in_sizes, int n_in,
                              void* d_out, int out_size, void* d_ws, size_t ws_size,
                              hipStream_t stream) {
  (void)in_sizes; (void)n_in; (void)d_ws; (void)ws_size; (void)out_size;
  const float* x  = (const float*)d_in[0];
  const float* W1 = (const float*)d_in[1];
  const float* b1 = (const float*)d_in[2];
  const float* W3 = (const float*)d_in[3];
  const float* b3 = (const float*)d_in[4];
  const float* W2 = (const float*)d_in[5];
  const float* b2 = (const float*)d_in[6];
  // d_in[7] = edge_index: fixed compile-time DAG; coefficients hard-coded.
  float* out = (float*)d_out;
  hipLaunchKernelGGL(gnn_kernel, dim3(NBLK), dim3(256), 0, stream,
                     x, W1, b1, W3, b3, W2, b2, out);
}

// Round 6
// 188.537 us; speedup vs baseline: 1.6747x; 1.0008x over previous
//
#include <hip/hip_runtime.h>
#include <hip/hip_bf16.h>

// 3-layer GCN, fixed 24-node DAG, batch 65536.
// Transposed-MFMA: each layer computes D^T = W^T * H^T with mfma_f32_16x16x32_bf16.
// Graph agg (fixed coeffs) + bias + relu fused into B-fragment build.
// Round-4 design (2nd resubmit; rounds 4-5 were infra acquisition timeouts):
// TWO independent sample-pair chains per wave (ILP x2) to fill the
// latency holes of the serial MFMA->pack->ds_write->ds_read->build chain.
// Rationale: true occupancy is ~2 waves/SIMD (VGPR_Count excludes AGPRs;
// unified-file total ~200), so TLP can't hide latency — ILP must.
// All LDS wave-private, no __syncthreads. o3 (f32) overlays hbuf.
// Do NOT cap registers below (256,2): round-2's (256,4) spilled 650 MB.

typedef __attribute__((ext_vector_type(8))) short bf16x8;
typedef __attribute__((ext_vector_type(4))) float f32x4;
typedef __attribute__((ext_vector_type(2))) float f32x2;

#define NBLK  1024
#define ITERS 4          // 4 samples per wave-iter; 1024 blk * 4 waves * 16 = 65536

__device__ __forceinline__ unsigned short f2bf(float f) {
  __hip_bfloat16 h = __float2bfloat16(f);
  return __builtin_bit_cast(unsigned short, h);
}
__device__ __forceinline__ f32x2 unpk(unsigned d) {
  f32x2 r;
  r.x = __builtin_bit_cast(float, d << 16);
  r.y = __builtin_bit_cast(float, d & 0xffff0000u);
  return r;
}
__device__ __forceinline__ unsigned pack2(f32x2 v) {
  return (unsigned)f2bf(v.x) | ((unsigned)f2bf(v.y) << 16);
}

union U16 { uint4 u; bf16x8 b; };

__device__ __forceinline__ bf16x8 pack8(const float v[8]) {
  U16 un;
  un.u.x = (unsigned)f2bf(v[0]) | ((unsigned)f2bf(v[1]) << 16);
  un.u.y = (unsigned)f2bf(v[2]) | ((unsigned)f2bf(v[3]) << 16);
  un.u.z = (unsigned)f2bf(v[4]) | ((unsigned)f2bf(v[5]) << 16);
  un.u.w = (unsigned)f2bf(v[6]) | ((unsigned)f2bf(v[7]) << 16);
  return un.b;
}

__global__ __launch_bounds__(256, 2)
void gnn_kernel(const float* __restrict__ xg,  const float* __restrict__ w1g,
                const float* __restrict__ b1g, const float* __restrict__ w3g,
                const float* __restrict__ b3g, const float* __restrict__ w2g,
                const float* __restrict__ b2g, float* __restrict__ outg) {
  // two wave-private LDS buffers per wave (chain A / chain B)
  __shared__ __align__(16) unsigned short hbuf_s[4][2][48 * 72];  // 2x6912 B per wave

  const int tid  = threadIdx.x;
  const int w    = tid >> 6;
  const int lane = tid & 63;
  const int l15  = lane & 15;
  const int g    = lane >> 4;
  unsigned short* hbA = hbuf_s[w][0];
  unsigned short* hbB = hbuf_s[w][1];
  const int wgid = blockIdx.x * 4 + w;

  // ---- static A-operand fragments (transposed weights), built once ----
  bf16x8 w1f[4], w3f[4][2], w2f[2];
  {
    float v[8];
    #pragma unroll
    for (int mi = 0; mi < 4; ++mi) {
      const int c = 16 * mi + l15;
      #pragma unroll
      for (int j = 0; j < 8; ++j) { int k = 8 * g + j; v[j] = (k < 10) ? w1g[k * 64 + c] : 0.f; }
      w1f[mi] = pack8(v);
      #pragma unroll
      for (int ki = 0; ki < 2; ++ki) {
        #pragma unroll
        for (int j = 0; j < 8; ++j) { int k = 32 * ki + 8 * g + j; v[j] = w3g[k * 64 + c]; }
        w3f[mi][ki] = pack8(v);
      }
    }
    #pragma unroll
    for (int ki = 0; ki < 2; ++ki) {
      #pragma unroll
      for (int j = 0; j < 8; ++j) {
        int k = 32 * ki + 8 * g + j;
        v[j] = (l15 < 10) ? w2g[k * 10 + l15] : 0.f;
      }
      w2f[ki] = pack8(v);
    }
  }

  // ---- per-lane bias registers as f32x2 pairs: bias[k], k = 32*ki + 8*g + 2*p+{0,1} ----
  f32x2 b1r[2][4], b3r[2][4];
  #pragma unroll
  for (int ki = 0; ki < 2; ++ki) {
    #pragma unroll
    for (int p = 0; p < 4; ++p) {
      const int k = 32 * ki + 8 * g + 2 * p;
      b1r[ki][p].x = b1g[k]; b1r[ki][p].y = b1g[k + 1];
      b3r[ki][p].x = b3g[k]; b3r[ki][p].y = b3g[k + 1];
    }
  }
  const float b2p = b2g[lane % 10];

  // ---- per-lane graph-agg coefficients for rows r = 16*ni + l15 ----
  int rowA[3], rowB[3], xoff[3];
  float csv[3], cabv[3];
  #pragma unroll
  for (int ni = 0; ni < 3; ++ni) {
    const int r   = 16 * ni + l15;
    const int sub = r / 24;
    const int n   = r - 24 * sub;
    csv[ni]  = (n < 2) ? 1.f : (1.f / 3.f);
    cabv[ni] = (n < 2) ? 0.f : ((n < 4) ? 0.57735026918962576f : (1.f / 3.f));
    const int sA = (n < 4) ? 0 : ((n & ~1) - 2);
    const int sB = (n < 4) ? 1 : ((n & ~1) - 1);
    rowA[ni] = 24 * sub + sA;
    rowB[ni] = 24 * sub + sB;
    xoff[ni] = sub * 240 + n * 10;
  }

  const f32x2 zero2 = {0.f, 0.f};
  const f32x4 zf = {0.f, 0.f, 0.f, 0.f};

  // B-frag builder: 3 source rows of pre-agg H -> packed-f32 combine -> bf16
  auto build = [&](const unsigned short* hb, int ni, int ki, const f32x2(&bias)[4]) -> bf16x8 {
    const int kbase = 32 * ki + 8 * g;
    const uint4 vS = *(const uint4*)(hb + (16 * ni + l15) * 72 + kbase);
    const uint4 vA = *(const uint4*)(hb + rowA[ni] * 72 + kbase);
    const uint4 vB = *(const uint4*)(hb + rowB[ni] * 72 + kbase);
    const f32x2 cs2  = {csv[ni], csv[ni]};
    const f32x2 cab2 = {cabv[ni], cabv[ni]};
    const unsigned aS[4] = {vS.x, vS.y, vS.z, vS.w};
    const unsigned aA[4] = {vA.x, vA.y, vA.z, vA.w};
    const unsigned aB[4] = {vB.x, vB.y, vB.z, vB.w};
    unsigned d[4];
    #pragma unroll
    for (int p = 0; p < 4; ++p) {
      f32x2 S = unpk(aS[p]);
      f32x2 t = unpk(aA[p]) + unpk(aB[p]);
      f32x2 v = __builtin_elementwise_fma(S, cs2, bias[p]);
      v = __builtin_elementwise_fma(t, cab2, v);
      v = __builtin_elementwise_max(v, zero2);
      d[p] = pack2(v);
    }
    U16 un; un.u.x = d[0]; un.u.y = d[1]; un.u.z = d[2]; un.u.w = d[3];
    return un.b;
  };

  // Layer-1: global X -> MFMA (K=10 zero-padded to 32)
  auto layer1 = [&](const float* xb, f32x4 (&acc)[4][3]) {
    #pragma unroll
    for (int ni = 0; ni < 3; ++ni) {
      float v[8] = {0.f, 0.f, 0.f, 0.f, 0.f, 0.f, 0.f, 0.f};
      const float* xr = xb + xoff[ni];
      if (g == 0) {
        float2 p0 = *(const float2*)(xr + 0);
        float2 p1 = *(const float2*)(xr + 2);
        float2 p2 = *(const float2*)(xr + 4);
        float2 p3 = *(const float2*)(xr + 6);
        v[0] = p0.x; v[1] = p0.y; v[2] = p1.x; v[3] = p1.y;
        v[4] = p2.x; v[5] = p2.y; v[6] = p3.x; v[7] = p3.y;
      } else if (g == 1) {
        float2 p4 = *(const float2*)(xr + 8);
        v[0] = p4.x; v[1] = p4.y;
      }
      bf16x8 bx = pack8(v);
      #pragma unroll
      for (int mi = 0; mi < 4; ++mi)
        acc[mi][ni] = __builtin_amdgcn_mfma_f32_16x16x32_bf16(w1f[mi], bx, zf, 0, 0, 0);
    }
  };

  // write pre-agg H (bf16): lane holds c = 16*mi+4*g+rr at row r = 16*ni+l15
  auto writeH = [&](unsigned short* hb, const f32x4 (&acc)[4][3]) {
    #pragma unroll
    for (int mi = 0; mi < 4; ++mi) {
      #pragma unroll
      for (int ni = 0; ni < 3; ++ni) {
        const int r = 16 * ni + l15, cb = 16 * mi + 4 * g;
        uint2 pk;
        pk.x = (unsigned)f2bf(acc[mi][ni][0]) | ((unsigned)f2bf(acc[mi][ni][1]) << 16);
        pk.y = (unsigned)f2bf(acc[mi][ni][2]) | ((unsigned)f2bf(acc[mi][ni][3]) << 16);
        *(uint2*)(hb + r * 72 + cb) = pk;
      }
    }
  };

  // Layer-2: builds from hb, MFMA into acc (in place)
  auto layer2 = [&](const unsigned short* hb, f32x4 (&acc)[4][3]) {
    #pragma unroll
    for (int ni = 0; ni < 3; ++ni) {
      bf16x8 bb0 = build(hb, ni, 0, b1r[0]);
      bf16x8 bb1 = build(hb, ni, 1, b1r[1]);
      #pragma unroll
      for (int mi = 0; mi < 4; ++mi) {
        f32x4 t = __builtin_amdgcn_mfma_f32_16x16x32_bf16(w3f[mi][0], bb0, zf, 0, 0, 0);
        acc[mi][ni] = __builtin_amdgcn_mfma_f32_16x16x32_bf16(w3f[mi][1], bb1, t, 0, 0, 0);
      }
    }
  };

  // Layer-3 + stage o3 (f32) over hb (hb dead after builds)
  auto layer3 = [&](unsigned short* hb) {
    f32x4 acc3[3];
    #pragma unroll
    for (int ni = 0; ni < 3; ++ni) {
      bf16x8 bb0 = build(hb, ni, 0, b3r[0]);
      bf16x8 bb1 = build(hb, ni, 1, b3r[1]);
      f32x4 t  = __builtin_amdgcn_mfma_f32_16x16x32_bf16(w2f[0], bb0, zf, 0, 0, 0);
      acc3[ni] = __builtin_amdgcn_mfma_f32_16x16x32_bf16(w2f[1], bb1, t, 0, 0, 0);
    }
    float* o3 = (float*)hb;
    #pragma unroll
    for (int ni = 0; ni < 3; ++ni) {
      const int r = 16 * ni + l15;
      *(f32x4*)(o3 + r * 20 + 4 * g) = acc3[ni];
    }
  };

  // epilogue: agg3 + b2 + relu, mean over 24 nodes, write 2 samples
  auto epilogue = [&](const unsigned short* hb, int s0) {
    const float* o3 = (const float*)hb;
    const int part = lane / 10;          // 0..5 valid (lane<60)
    const int pc   = lane - 10 * part;   // output channel 0..9
    #pragma unroll
    for (int sub = 0; sub < 2; ++sub) {
      float sum = 0.f;
      if (lane < 60) {
        const int rb = 24 * sub;
        #pragma unroll
        for (int dn = 0; dn < 4; ++dn) {
          const int n = 4 * part + dn;
          const float cs  = (n < 2) ? 1.f : (1.f / 3.f);
          const float cab = (n < 2) ? 0.f : ((n < 4) ? 0.57735026918962576f : (1.f / 3.f));
          const int sA = (n < 4) ? 0 : ((n & ~1) - 2);
          const int sB = (n < 4) ? 1 : ((n & ~1) - 1);
          const float vv = cs * o3[(rb + n) * 20 + pc]
                         + cab * (o3[(rb + sA) * 20 + pc] + o3[(rb + sB) * 20 + pc]);
          sum += fmaxf(vv + b2p, 0.f);
        }
      }
      float s1 = sum + __shfl_down(sum, 30);
      float t1 = __shfl_down(s1, 10);
      float t2 = __shfl_down(s1, 20);
      float tot = s1 + t1 + t2;
      if (lane < 10) outg[(long)(s0 + sub) * 10 + lane] = tot * (1.f / 24.f);
    }
  };

  for (int it = 0; it < ITERS; ++it) {
    const int sA = wgid * 16 + it * 4;      // chain A: samples sA, sA+1
    const int sB = sA + 2;                  // chain B: samples sB, sB+1
    const float* xbA = xg + (long)sA * 240;
    const float* xbB = xg + (long)sB * 240;

    f32x4 accA[4][3], accB[4][3];

    layer1(xbA, accA);
    layer1(xbB, accB);
    writeH(hbA, accA);
    writeH(hbB, accB);

    layer2(hbA, accA);
    layer2(hbB, accB);
    writeH(hbA, accA);
    writeH(hbB, accB);

    layer3(hbA);
    layer3(hbB);

    epilogue(hbA, sA);
    epilogue(hbB, sB);
  }
}

extern "C" void kernel_launch(void* const* d_in, const int* in_sizes, int n_in,
                              void* d_out, int out_size, void* d_ws, size_t ws_size,
                              hipStream_t stream) {
  (void)in_sizes; (void)n_in; (void)d_ws; (void)ws_size; (void)out_size;
  const float* x  = (const float*)d_in[0];
  const float* W1 = (const float*)d_in[1];
  const float* b1 = (const float*)d_in[2];
  const float* W3 = (const float*)d_in[3];
  const float* b3 = (const float*)d_in[4];
  const float* W2 = (const float*)d_in[5];
  const float* b2 = (const float*)d_in[6];
  // d_in[7] = edge_index: fixed compile-time DAG; coefficients hard-coded.
  float* out = (float*)d_out;
  hipLaunchKernelGGL(gnn_kernel, dim3(NBLK), dim3(256), 0, stream,
                     x, W1, b1, W3, b3, W2, b2, out);
}

// Round 7
// 183.505 us; speedup vs baseline: 1.7206x; 1.0274x over previous
//
#include <hip/hip_runtime.h>
#include <hip/hip_bf16.h>

// 3-layer GCN, fixed 24-node DAG, batch 65536.  Round-7 redesign:
// EVERYTHING is MFMA. The graph aggregation agg(H)=A_norm*H is itself a
// matmul with a constant 24x24 matrix, so the chain is 6 MFMA stages:
//   S1: T1 = X*W1            (contract feat)
//   S2: G1 = relu(3*(Amix*T1 + b1))   (contract node; bias via ones-col k=48)
//   S3: T2 = G1*(W3/3)       (contract ch)
//   S4: G2 = relu(3*(Amix*T2 + b3))   (contract node)
//   S5: T3 = G2*(W2/3)       (contract ch)
//   S6: out = mean(relu(3*(Amix*T3 + b2)))/3   (contract node; /72 total)
// Alternating-transpose storage: C-layout has M on (g,reg), N on lane&15, so
// storing [N][M] is contiguous b64; next stage contracts prev-M and its
// A-frag reads [N][M] rows contiguously (b128). No VALU combines, no builds.
// Amix scaled by 3 so coeffs {1,3,sqrt3} are (near-)exact bf16; 1/3 folded
// into static W3, W2 and the final mean scale (1/72).
// All LDS wave-private, no __syncthreads (same-wave DS ops are in-order).
// Do NOT cap registers below (256,2): round-2's (256,4) spilled 650 MB.

typedef __attribute__((ext_vector_type(8))) short bf16x8;
typedef __attribute__((ext_vector_type(4))) float f32x4;

#define NBLK  1024
#define ITERS 8          // 2 samples (1 pair) per iter; 1024*4*16 = 65536

__device__ __forceinline__ unsigned short f2bf(float f) {
  __hip_bfloat16 h = __float2bfloat16(f);
  return __builtin_bit_cast(unsigned short, h);
}

union U16 { uint4 u; bf16x8 b; };

__device__ __forceinline__ bf16x8 pack8(const float v[8]) {
  U16 un;
  un.u.x = (unsigned)f2bf(v[0]) | ((unsigned)f2bf(v[1]) << 16);
  un.u.y = (unsigned)f2bf(v[2]) | ((unsigned)f2bf(v[3]) << 16);
  un.u.z = (unsigned)f2bf(v[4]) | ((unsigned)f2bf(v[5]) << 16);
  un.u.w = (unsigned)f2bf(v[6]) | ((unsigned)f2bf(v[7]) << 16);
  return un.b;
}
__device__ __forceinline__ uint2 pk4(f32x4 a) {
  uint2 r;
  r.x = (unsigned)f2bf(a[0]) | ((unsigned)f2bf(a[1]) << 16);
  r.y = (unsigned)f2bf(a[2]) | ((unsigned)f2bf(a[3]) << 16);
  return r;
}
__device__ __forceinline__ uint2 pk4r(f32x4 a) {
  const f32x4 z = {0.f, 0.f, 0.f, 0.f};
  return pk4(__builtin_elementwise_max(a, z));
}

__global__ __launch_bounds__(256, 2)
void gnn_kernel(const float* __restrict__ xg,  const float* __restrict__ w1g,
                const float* __restrict__ b1g, const float* __restrict__ w3g,
                const float* __restrict__ b3g, const float* __restrict__ w2g,
                const float* __restrict__ b2g, float* __restrict__ outg) {
  // wave-private LDS, pitch 72 (bank spread). bufA: [64 rows][72] (T1 [ch][node],
  // then T2 [ch'][node']; col 48 = bias b1 / b3, cols 49..71 zero).
  // bufB: [48][72] ([node][ch], G1 then G2). bufD: [16][72] (T3 [c][node], col48=b2).
  __shared__ __align__(16) unsigned short bufA_s[4][64 * 72];
  __shared__ __align__(16) unsigned short bufB_s[4][48 * 72];
  __shared__ __align__(16) unsigned short bufD_s[4][16 * 72];

  const int tid  = threadIdx.x;
  const int w    = tid >> 6;
  const int lane = tid & 63;
  const int l15  = lane & 15;
  const int g    = lane >> 4;
  unsigned short* bA = bufA_s[w];
  unsigned short* bB = bufB_s[w];
  unsigned short* bD = bufD_s[w];
  const int wgid = blockIdx.x * 4 + w;

  // ---- static fragments ----
  bf16x8 w1bf[4], w3f[4][2], w2f[2], amixB[3][2];
  {
    float v[8];
    #pragma unroll
    for (int nc = 0; nc < 4; ++nc) {
      #pragma unroll
      for (int j = 0; j < 8; ++j) { int k = 8 * g + j; v[j] = (k < 10) ? w1g[k * 64 + 16 * nc + l15] : 0.f; }
      w1bf[nc] = pack8(v);
      #pragma unroll
      for (int ks = 0; ks < 2; ++ks) {
        #pragma unroll
        for (int j = 0; j < 8; ++j) v[j] = w3g[(32 * ks + 8 * g + j) * 64 + 16 * nc + l15] * (1.f / 3.f);
        w3f[nc][ks] = pack8(v);
      }
    }
    #pragma unroll
    for (int ks = 0; ks < 2; ++ks) {
      #pragma unroll
      for (int j = 0; j < 8; ++j) {
        int k = 32 * ks + 8 * g + j;
        v[j] = (l15 < 10) ? w2g[k * 10 + l15] * (1.f / 3.f) : 0.f;
      }
      w2f[ks] = pack8(v);
    }
    // Amix_ext (x3): B-frag (n = node_out = 16*nn+l15, k = node_in; k==48 -> 3 = bias row)
    #pragma unroll
    for (int nn = 0; nn < 3; ++nn) {
      #pragma unroll
      for (int ks = 0; ks < 2; ++ks) {
        #pragma unroll
        for (int j = 0; j < 8; ++j) {
          const int k = 32 * ks + 8 * g + j, n = 16 * nn + l15;
          float c = 0.f;
          if (k == 48) c = 3.f;
          else if (k < 48 && (k / 24) == (n / 24)) {
            const int s = k % 24, t = n % 24;
            if (t < 2)      c = (s == t) ? 3.f : 0.f;
            else if (t < 4) c = (s == t) ? 1.f : ((s < 2) ? 1.7320508075688772f : 0.f);
            else { const int sa = (t & ~1) - 2; c = (s == t || s == sa || s == sa + 1) ? 1.f : 0.f; }
          }
          v[j] = c;
        }
        amixB[nn][ks] = pack8(v);
      }
    }
  }

  const unsigned short b1f = f2bf(b1g[lane]);   // lane = ch
  const unsigned short b3f = f2bf(b3g[lane]);

  // one-time LDS init: zero bufA/bufD cols 48..71 (read-as-zero pads; static-B
  // rows 49..63 are 0 but stale LDS could hold NaN patterns -> must zero). b2 col.
  {
    const uint4 z4 = {0, 0, 0, 0};
    *(uint4*)&bA[lane * 72 + 48] = z4;
    *(uint4*)&bA[lane * 72 + 56] = z4;
    *(uint4*)&bA[lane * 72 + 64] = z4;
    if (lane < 16) {
      *(uint4*)&bD[lane * 72 + 48] = z4;
      *(uint4*)&bD[lane * 72 + 56] = z4;
      *(uint4*)&bD[lane * 72 + 64] = z4;
      bD[lane * 72 + 48] = (lane < 10) ? f2bf(b2g[lane]) : (unsigned short)0;
    }
  }

  // X gather offsets: A-frag rows r = 16*mt + l15 (pair-space node)
  int xoff[3];
  #pragma unroll
  for (int mt = 0; mt < 3; ++mt) {
    const int r = 16 * mt + l15, sub = r / 24, n = r - 24 * sub;
    xoff[mt] = sub * 240 + n * 10;
  }

  const f32x4 zf = {0.f, 0.f, 0.f, 0.f};

  for (int it = 0; it < ITERS; ++it) {
    const int sp = wgid * 16 + it * 2;           // pair = samples sp, sp+1
    const float* xb = xg + (long)sp * 240;

    bA[lane * 72 + 48] = b1f;                    // bias-1 column for S2

    // ---------- S1: T1[node][ch] = X*W1 (K=10 pad 32); store bufA[ch][node] ----------
    f32x4 acc1[3][4];
    #pragma unroll
    for (int mt = 0; mt < 3; ++mt) {
      float v[8] = {0.f, 0.f, 0.f, 0.f, 0.f, 0.f, 0.f, 0.f};
      const float* xr = xb + xoff[mt];
      if (g == 0) {
        float2 p0 = *(const float2*)(xr + 0);
        float2 p1 = *(const float2*)(xr + 2);
        float2 p2 = *(const float2*)(xr + 4);
        float2 p3 = *(const float2*)(xr + 6);
        v[0] = p0.x; v[1] = p0.y; v[2] = p1.x; v[3] = p1.y;
        v[4] = p2.x; v[5] = p2.y; v[6] = p3.x; v[7] = p3.y;
      } else if (g == 1) {
        float2 p4 = *(const float2*)(xr + 8);
        v[0] = p4.x; v[1] = p4.y;
      }
      bf16x8 ax = pack8(v);
      #pragma unroll
      for (int nc = 0; nc < 4; ++nc)
        acc1[mt][nc] = __builtin_amdgcn_mfma_f32_16x16x32_bf16(ax, w1bf[nc], zf, 0, 0, 0);
    }
    #pragma unroll
    for (int mt = 0; mt < 3; ++mt)
      #pragma unroll
      for (int nc = 0; nc < 4; ++nc)
        *(uint2*)&bA[(16 * nc + l15) * 72 + 16 * mt + 4 * g] = pk4(acc1[mt][nc]);

    // ---------- S2: G1' = relu(3*(Amix*T1+b1)); A=bufA[ch][node], B=amixB ----------
    U16 a2[4][2];
    #pragma unroll
    for (int mi = 0; mi < 4; ++mi)
      #pragma unroll
      for (int ks = 0; ks < 2; ++ks)
        a2[mi][ks].u = *(const uint4*)&bA[(16 * mi + l15) * 72 + 32 * ks + 8 * g];
    bA[lane * 72 + 48] = b3f;                    // after S2 reads: bias-3 col for S4
    f32x4 acc2[4][3];
    #pragma unroll
    for (int mi = 0; mi < 4; ++mi)
      #pragma unroll
      for (int nn = 0; nn < 3; ++nn) {
        f32x4 t = __builtin_amdgcn_mfma_f32_16x16x32_bf16(a2[mi][0].b, amixB[nn][0], zf, 0, 0, 0);
        acc2[mi][nn] = __builtin_amdgcn_mfma_f32_16x16x32_bf16(a2[mi][1].b, amixB[nn][1], t, 0, 0, 0);
      }
    #pragma unroll
    for (int mi = 0; mi < 4; ++mi)
      #pragma unroll
      for (int nn = 0; nn < 3; ++nn)
        *(uint2*)&bB[(16 * nn + l15) * 72 + 16 * mi + 4 * g] = pk4r(acc2[mi][nn]);

    // ---------- S3: T2[node'][ch'] = G1'*(W3/3); A=bufB[node'][ch], store bufA[ch'][node'] ----------
    U16 a3[3][2];
    #pragma unroll
    for (int mt = 0; mt < 3; ++mt)
      #pragma unroll
      for (int ks = 0; ks < 2; ++ks)
        a3[mt][ks].u = *(const uint4*)&bB[(16 * mt + l15) * 72 + 32 * ks + 8 * g];
    f32x4 acc3[3][4];
    #pragma unroll
    for (int mt = 0; mt < 3; ++mt)
      #pragma unroll
      for (int nc = 0; nc < 4; ++nc) {
        f32x4 t = __builtin_amdgcn_mfma_f32_16x16x32_bf16(a3[mt][0].b, w3f[nc][0], zf, 0, 0, 0);
        acc3[mt][nc] = __builtin_amdgcn_mfma_f32_16x16x32_bf16(a3[mt][1].b, w3f[nc][1], t, 0, 0, 0);
      }
    #pragma unroll
    for (int mt = 0; mt < 3; ++mt)
      #pragma unroll
      for (int nc = 0; nc < 4; ++nc)
        *(uint2*)&bA[(16 * nc + l15) * 72 + 16 * mt + 4 * g] = pk4(acc3[mt][nc]);

    // ---------- S4: G2' = relu(3*(Amix*T2+b3)) ----------
    U16 a4[4][2];
    #pragma unroll
    for (int mi = 0; mi < 4; ++mi)
      #pragma unroll
      for (int ks = 0; ks < 2; ++ks)
        a4[mi][ks].u = *(const uint4*)&bA[(16 * mi + l15) * 72 + 32 * ks + 8 * g];
    f32x4 acc4[4][3];
    #pragma unroll
    for (int mi = 0; mi < 4; ++mi)
      #pragma unroll
      for (int nn = 0; nn < 3; ++nn) {
        f32x4 t = __builtin_amdgcn_mfma_f32_16x16x32_bf16(a4[mi][0].b, amixB[nn][0], zf, 0, 0, 0);
        acc4[mi][nn] = __builtin_amdgcn_mfma_f32_16x16x32_bf16(a4[mi][1].b, amixB[nn][1], t, 0, 0, 0);
      }
    #pragma unroll
    for (int mi = 0; mi < 4; ++mi)
      #pragma unroll
      for (int nn = 0; nn < 3; ++nn)
        *(uint2*)&bB[(16 * nn + l15) * 72 + 16 * mi + 4 * g] = pk4r(acc4[mi][nn]);

    // ---------- S5: T3[node''][c] = G2'*(W2/3); store bufD[c][node''] ----------
    U16 a5[3][2];
    #pragma unroll
    for (int mt = 0; mt < 3; ++mt)
      #pragma unroll
      for (int ks = 0; ks < 2; ++ks)
        a5[mt][ks].u = *(const uint4*)&bB[(16 * mt + l15) * 72 + 32 * ks + 8 * g];
    f32x4 acc5[3];
    #pragma unroll
    for (int mt = 0; mt < 3; ++mt) {
      f32x4 t = __builtin_amdgcn_mfma_f32_16x16x32_bf16(a5[mt][0].b, w2f[0], zf, 0, 0, 0);
      acc5[mt] = __builtin_amdgcn_mfma_f32_16x16x32_bf16(a5[mt][1].b, w2f[1], t, 0, 0, 0);
    }
    #pragma unroll
    for (int mt = 0; mt < 3; ++mt)
      *(uint2*)&bD[l15 * 72 + 16 * mt + 4 * g] = pk4(acc5[mt]);

    // ---------- S6: G3' rows=c (4g+r), cols=node (16nt+l15); Amix*T3 + b2 ----------
    U16 a6[2];
    #pragma unroll
    for (int ks = 0; ks < 2; ++ks)
      a6[ks].u = *(const uint4*)&bD[l15 * 72 + 32 * ks + 8 * g];
    f32x4 acc6[3];
    #pragma unroll
    for (int nt = 0; nt < 3; ++nt) {
      f32x4 t = __builtin_amdgcn_mfma_f32_16x16x32_bf16(a6[0].b, amixB[nt][0], zf, 0, 0, 0);
      acc6[nt] = __builtin_amdgcn_mfma_f32_16x16x32_bf16(a6[1].b, amixB[nt][1], t, 0, 0, 0);
    }

    // ---------- epilogue: relu, mean over nodes (sample split at node 24) ----------
    {
      f32x4 v0 = __builtin_elementwise_max(acc6[0], zf);
      f32x4 v1 = __builtin_elementwise_max(acc6[1], zf);
      f32x4 v2 = __builtin_elementwise_max(acc6[2], zf);
      f32x4 sum0 = v0, sum1 = v2;
      if (l15 < 8) sum0 += v1; else sum1 += v1;
      #pragma unroll
      for (int d = 1; d < 16; d <<= 1) {
        #pragma unroll
        for (int r = 0; r < 4; ++r) {
          sum0[r] += __shfl_xor(sum0[r], d);
          sum1[r] += __shfl_xor(sum1[r], d);
        }
      }
      if (l15 < 2) {
        const f32x4 s = (l15 == 0) ? sum0 : sum1;
        const float sc = 1.f / 72.f;              // mean/24 and the /3 Amix scale
        const long  so = (long)(sp + l15) * 10;
        if (g < 3) { float2 t0 = {s[0] * sc, s[1] * sc}; *(float2*)&outg[so + 4 * g] = t0; }
        if (g < 2) { float2 t1 = {s[2] * sc, s[3] * sc}; *(float2*)&outg[so + 4 * g + 2] = t1; }
      }
    }
  }
}

extern "C" void kernel_launch(void* const* d_in, const int* in_sizes, int n_in,
                              void* d_out, int out_size, void* d_ws, size_t ws_size,
                              hipStream_t stream) {
  (void)in_sizes; (void)n_in; (void)d_ws; (void)ws_size; (void)out_size;
  const float* x  = (const float*)d_in[0];
  const float* W1 = (const float*)d_in[1];
  const float* b1 = (const float*)d_in[2];
  const float* W3 = (const float*)d_in[3];
  const float* b3 = (const float*)d_in[4];
  const float* W2 = (const float*)d_in[5];
  const float* b2 = (const float*)d_in[6];
  // d_in[7] = edge_index: fixed compile-time DAG; Amix coefficients hard-coded.
  float* out = (float*)d_out;
  hipLaunchKernelGGL(gnn_kernel, dim3(NBLK), dim3(256), 0, stream,
                     x, W1, b1, W3, b3, W2, b2, out);
}